// Round 1
// baseline (109.313 us; speedup 1.0000x reference)
//
#include <hip/hip_runtime.h>

// Problem constants (from reference): B=4, C=5, H=64, W=64, N=4096
#define Bq  4
#define Cc  5
#define Hh  64
#define Ww  64
#define HW  (Hh * Ww)       // 4096
#define CHW (Cc * HW)       // 20480

// ---------------------------------------------------------------------------
// Kernel A: K/V map precompute.  One thread per (b, p) spatial position.
// K[b,o,p] = sum_c kw[o,c]*x[b,c,p] + kb[o];  V likewise.
// ---------------------------------------------------------------------------
__global__ void kv_precompute(const float* __restrict__ x,
                              const float* __restrict__ kw, const float* __restrict__ kb,
                              const float* __restrict__ vw, const float* __restrict__ vb,
                              float* __restrict__ K, float* __restrict__ V) {
    int t = blockIdx.x * blockDim.x + threadIdx.x;
    if (t >= Bq * HW) return;
    int b = t >> 12;          // / HW
    int p = t & (HW - 1);     // % HW
    float xi[Cc];
#pragma unroll
    for (int c = 0; c < Cc; ++c) xi[c] = x[b * CHW + c * HW + p];
#pragma unroll
    for (int o = 0; o < Cc; ++o) {
        float kacc = kb[o], vacc = vb[o];
#pragma unroll
        for (int c = 0; c < Cc; ++c) {
            kacc += kw[o * Cc + c] * xi[c];
            vacc += vw[o * Cc + c] * xi[c];
        }
        K[b * CHW + o * HW + p] = kacc;
        V[b * CHW + o * HW + p] = vacc;
    }
}

// ---------------------------------------------------------------------------
// Kernel B: one 64-lane wave per query n.  Online softmax over HW keys,
// butterfly shuffle-merge, scatter gamma*out + xi into y.
// USE_WS: read precomputed K/V from workspace; else compute from x inline.
// ---------------------------------------------------------------------------
template <bool USE_WS>
__global__ void attn_scatter(const float* __restrict__ x,
                             const float* __restrict__ qw, const float* __restrict__ qb,
                             const float* __restrict__ kw, const float* __restrict__ kb,
                             const float* __restrict__ vw, const float* __restrict__ vb,
                             const float* __restrict__ K, const float* __restrict__ V,
                             const float* __restrict__ gamma,
                             const int* __restrict__ idx_b, const int* __restrict__ idx_h,
                             const int* __restrict__ idx_w,
                             float* __restrict__ y, int N) {
    int gtid = blockIdx.x * blockDim.x + threadIdx.x;
    int n    = gtid >> 6;     // wave id
    int lane = threadIdx.x & 63;
    if (n >= N) return;

    const int b   = idx_b[n];
    const int pos = idx_h[n] * Ww + idx_w[n];

    // q[o] = sum_c qw[o,c]*x[b,c,pos] + qb[o]   (same in every lane; broadcast loads)
    float xq[Cc];
#pragma unroll
    for (int c = 0; c < Cc; ++c) xq[c] = x[b * CHW + c * HW + pos];
    float q[Cc];
#pragma unroll
    for (int o = 0; o < Cc; ++o) {
        float a = qb[o];
#pragma unroll
        for (int c = 0; c < Cc; ++c) a += qw[o * Cc + c] * xq[c];
        q[o] = a;
    }

    const float* Kb = K + b * CHW;
    const float* Vb = V + b * CHW;
    const float* Xb = x + b * CHW;

    float m = -1e30f, l = 0.f;
    float acc[Cc] = {0.f, 0.f, 0.f, 0.f, 0.f};

    for (int p = lane; p < HW; p += 64) {
        float kv_k[Cc], kv_v[Cc];
        if (USE_WS) {
#pragma unroll
            for (int c = 0; c < Cc; ++c) {
                kv_k[c] = Kb[c * HW + p];
                kv_v[c] = Vb[c * HW + p];
            }
        } else {
            float xi[Cc];
#pragma unroll
            for (int c = 0; c < Cc; ++c) xi[c] = Xb[c * HW + p];
#pragma unroll
            for (int o = 0; o < Cc; ++o) {
                float ka = kb[o], va = vb[o];
#pragma unroll
                for (int c = 0; c < Cc; ++c) {
                    ka += kw[o * Cc + c] * xi[c];
                    va += vw[o * Cc + c] * xi[c];
                }
                kv_k[o] = ka;
                kv_v[o] = va;
            }
        }
        float e = q[0] * kv_k[0] + q[1] * kv_k[1] + q[2] * kv_k[2] +
                  q[3] * kv_k[3] + q[4] * kv_k[4];
        float nm  = fmaxf(m, e);
        float a   = __expf(m - nm);   // 1.0 when m unchanged; 0 on first iter
        float wgt = __expf(e - nm);
        l = l * a + wgt;
#pragma unroll
        for (int c = 0; c < Cc; ++c) acc[c] = acc[c] * a + wgt * kv_v[c];
        m = nm;
    }

    // Butterfly merge of (m, l, acc[5]) across the 64-lane wave.
#pragma unroll
    for (int off = 32; off >= 1; off >>= 1) {
        float m2 = __shfl_xor(m, off, 64);
        float l2 = __shfl_xor(l, off, 64);
        float nm = fmaxf(m, m2);
        float a  = __expf(m - nm);
        float a2 = __expf(m2 - nm);
        l = l * a + l2 * a2;
#pragma unroll
        for (int c = 0; c < Cc; ++c) {
            float o2 = __shfl_xor(acc[c], off, 64);
            acc[c] = acc[c] * a + o2 * a2;
        }
        m = nm;
    }

    if (lane < Cc) {
        int c = lane;
        float xi = x[b * CHW + c * HW + pos];
        y[b * CHW + c * HW + pos] = gamma[0] * (acc[c] / l) + xi;
    }
}

// ---------------------------------------------------------------------------
extern "C" void kernel_launch(void* const* d_in, const int* in_sizes, int n_in,
                              void* d_out, int out_size, void* d_ws, size_t ws_size,
                              hipStream_t stream) {
    const float* x     = (const float*)d_in[0];
    // d_in[1] = x_teature: unused by the reference
    const float* qw    = (const float*)d_in[2];
    const float* qb    = (const float*)d_in[3];
    const float* kw    = (const float*)d_in[4];
    const float* kb    = (const float*)d_in[5];
    const float* vw    = (const float*)d_in[6];
    const float* vb    = (const float*)d_in[7];
    const float* gamma = (const float*)d_in[8];
    const int*   idx_b = (const int*)d_in[9];
    const int*   idx_h = (const int*)d_in[10];
    const int*   idx_w = (const int*)d_in[11];
    const int    N     = in_sizes[9];   // idx_b element count (= index_len)

    float* y = (float*)d_out;

    // y starts as a copy of x (scatter happens on top).
    hipMemcpyAsync(y, x, (size_t)Bq * CHW * sizeof(float),
                   hipMemcpyDeviceToDevice, stream);

    const size_t kv_bytes = (size_t)2 * Bq * CHW * sizeof(float); // 640 KB
    const int wavesPerBlock = 4;                   // 256 threads
    const int grid_b = (N + wavesPerBlock - 1) / wavesPerBlock;

    if (ws_size >= kv_bytes) {
        float* K = (float*)d_ws;
        float* V = K + (size_t)Bq * CHW;
        kv_precompute<<<(Bq * HW + 255) / 256, 256, 0, stream>>>(x, kw, kb, vw, vb, K, V);
        attn_scatter<true><<<grid_b, 256, 0, stream>>>(
            x, qw, qb, kw, kb, vw, vb, K, V, gamma, idx_b, idx_h, idx_w, y, N);
    } else {
        attn_scatter<false><<<grid_b, 256, 0, stream>>>(
            x, qw, qb, kw, kb, vw, vb, nullptr, nullptr, gamma, idx_b, idx_h, idx_w, y, N);
    }
}